// Round 18
// baseline (6973.191 us; speedup 1.0000x reference)
//
#include <hip/hip_runtime.h>
#include <hip/hip_bf16.h>

#define BB 64
#define TT 2048
#define HH 256
#define H4 1024
#define NC 10
#define CH 32            // steps per chunk
#define NCH (TT / CH)    // 64 chunks
#define NR 4             // gx ring slots

typedef _Float16 half2v __attribute__((ext_vector_type(2)));
typedef _Float16 half8  __attribute__((ext_vector_type(8)));
typedef float    f32x4  __attribute__((ext_vector_type(4)));

struct __align__(128) Line { unsigned v; unsigned pad[31]; };

__device__ __forceinline__ float fsig_(float x) {
    return __fdividef(1.f, 1.f + __expf(-x));
}
__device__ __forceinline__ float ftanh_(float x) {
    return 1.f - __fdividef(2.f, __expf(2.f * x) + 1.f);
}

__device__ __forceinline__ float fdot2_(unsigned wu, half2v hv, float acc) {
#if __has_builtin(__builtin_amdgcn_fdot2)
    return __builtin_amdgcn_fdot2(__builtin_bit_cast(half2v, wu), hv, acc, false);
#else
    half2v w = __builtin_bit_cast(half2v, wu);
    return acc + (float)w[0] * (float)hv[0] + (float)w[1] * (float)hv[1];
#endif
}

// wave-0 parallel poll of 64 flags; one acquire fence; releases whole WG.
__device__ __forceinline__ void wait_flags(Line* f, unsigned target, int tid) {
    if (tid < 64) {
        while (true) {
            unsigned v = __hip_atomic_load(&f[tid].v, __ATOMIC_RELAXED,
                                           __HIP_MEMORY_SCOPE_AGENT);
            if (__all(v >= target)) break;
            __builtin_amdgcn_s_sleep(2);
        }
        if (tid == 0)
            __builtin_amdgcn_fence(__ATOMIC_ACQUIRE, "agent");
    }
    __syncthreads();
}

// ---------------------------------------------------------------------------
__global__ void f32_to_f16(const float* __restrict__ in,
                           _Float16* __restrict__ out, int n8)
{
    int i = blockIdx.x * 256 + threadIdx.x;
    if (i >= n8) return;
    float4 v0 = ((const float4*)in)[2 * i];
    float4 v1 = ((const float4*)in)[2 * i + 1];
    half8 h;
    h[0] = (_Float16)v0.x; h[1] = (_Float16)v0.y;
    h[2] = (_Float16)v0.z; h[3] = (_Float16)v0.w;
    h[4] = (_Float16)v1.x; h[5] = (_Float16)v1.y;
    h[6] = (_Float16)v1.z; h[7] = (_Float16)v1.w;
    ((half8*)out)[i] = h;
}

// ---------------------------------------------------------------------------
__global__ void prep_w(const float* __restrict__ W, uint4* __restrict__ out)
{
    const int k2 = blockIdx.x, t = threadIdx.x;
    unsigned q4[4];
#pragma unroll
    for (int q = 0; q < 4; q++) {
        const float* wr = W + (size_t)(q * 256 + t) * 256 + 2 * k2;
        union { _Float16 h[2]; unsigned u; } cv;
        cv.h[0] = (_Float16)wr[0];
        cv.h[1] = (_Float16)wr[1];
        q4[q] = cv.u;
    }
    out[(size_t)k2 * 256 + t] = make_uint4(q4[0], q4[1], q4[2], q4[3]);
}

// ---------------------------------------------------------------------------
// 4-role pipelined persistent kernel, 256 WGs x 256 threads:
//  role0 wg[0,64)   : L1 recurrence  role1 wg[64,128) : gemm1 (x16*Wih0)
//  role2 wg[128,192): gemm2 (h1c*Wih1)  role3 wg[192,256): L2 recurrence
// REC = FULL-UNIT-PER-THREAD: thread tau owns unit tau (4 gates, K=256).
//  - ONE barrier per step (no partial exchange), gates fully parallel
//  - weights: 96 quads volatile-resident (384 dwords; 1 wave/SIMD ->
//    512-reg unified budget, ~128V+256A) + 32 quads LDS (128 KB)
// gx gate-interleaved [tc][b][u*4+q] -> one uint2 per thread per step.
// ---------------------------------------------------------------------------
__global__ __launch_bounds__(256, 1)
void lstm_pipe(const _Float16* __restrict__ x16,
               const _Float16* __restrict__ w16a, const _Float16* __restrict__ w16b,
               const float* __restrict__ bih0, const float* __restrict__ bhh0,
               const float* __restrict__ bih1, const float* __restrict__ bhh1,
               const uint4* __restrict__ wpk0, const uint4* __restrict__ wpk1,
               _Float16* __restrict__ gx1r, _Float16* __restrict__ gx2r,
               _Float16* __restrict__ h1c,
               float* __restrict__ hs1, float* __restrict__ cs1,
               float* __restrict__ hs2, float* __restrict__ cs2,
               Line* __restrict__ fG1, Line* __restrict__ fL1,
               Line* __restrict__ fG2, Line* __restrict__ fL2)
{
    __shared__ __align__(16) unsigned char pool[1088 + 32 * 4096];
    _Float16* hlb = (_Float16*)pool;              // [2][272] halves
    uint4*    wl  = (uint4*)(pool + 1088);        // [32][256] quads (128 KB)

    const int wg = blockIdx.x, tid = threadIdx.x;
    const int role = wg >> 6, sub = wg & 63;

    if (role == 1 || role == 2) {
        // ---------------- gemm worker (4 waves, 2 n-passes) ----------------
        const bool isG2 = (role == 2);
        const _Float16* A  = isG2 ? h1c  : x16;
        const _Float16* Wm = isG2 ? w16b : w16a;
        const float* b1 = isG2 ? bih1 : bih0;
        const float* b2 = isG2 ? bhh1 : bhh0;
        _Float16* outr  = isG2 ? gx2r : gx1r;
        Line* fOut      = isG2 ? fG2  : fG1;

        const int v = tid >> 6, lane = tid & 63;
        const int lrow = lane & 15, lkg = lane >> 4;
        const int tcl = sub & 31, nhalf = sub >> 5;

        for (int c = 0; c < NCH; c++) {
            if (isG2) {
                wait_flags(fL1, (unsigned)(c + 1), tid);
                if (c >= NR) wait_flags(fL2, (unsigned)(c - (NR - 1)), tid);
            } else {
                if (c >= NR) wait_flags(fL1, (unsigned)(c - (NR - 1)), tid);
            }
            const int tc = c * CH + tcl;
            const int slot = c % NR;
            const _Float16* arow =
                A + ((size_t)(v * 16 + lrow) * TT + tc) * 256 + lkg * 8;
            const int bout = v * 16 + lkg * 4;

#pragma unroll
            for (int pass = 0; pass < 2; pass++) {
                const int n0 = nhalf * 512 + pass * 256;
                const _Float16* wrow = Wm + (size_t)(n0 + lrow) * 256 + lkg * 8;
                f32x4 acc[16];
#pragma unroll
                for (int j = 0; j < 16; j++) acc[j] = (f32x4)(0.f);
#pragma unroll
                for (int k0 = 0; k0 < 256; k0 += 32) {
                    half8 a = *(const half8*)(arow + k0);
#pragma unroll
                    for (int j = 0; j < 16; j++) {
                        half8 bf = *(const half8*)(wrow + (size_t)j * 16 * 256 + k0);
                        acc[j] = __builtin_amdgcn_mfma_f32_16x16x32_f16(a, bf, acc[j], 0, 0, 0);
                    }
                }
#pragma unroll
                for (int j = 0; j < 16; j++) {
                    int n = n0 + j * 16 + lrow;
                    float bsum = b1[n] + b2[n];
                    int u = n & 255, q = n >> 8;   // gate-interleaved target
#pragma unroll
                    for (int r = 0; r < 4; r++) {
                        outr[((size_t)(slot * CH + tcl) * BB + bout + r) * H4 + u * 4 + q] =
                            (_Float16)(acc[j][r] + bsum);
                    }
                }
            }
            __syncthreads();   // drain this WG's stores
            if (tid == 0) {
                __builtin_amdgcn_fence(__ATOMIC_RELEASE, "agent");
                __hip_atomic_store(&fOut[sub].v, (unsigned)(c + 1),
                                   __ATOMIC_RELAXED, __HIP_MEMORY_SCOPE_AGENT);
            }
        }
        return;
    }

    // ---------------- recurrence (role 0 = L1, role 3 = L2) ----------------
    const bool isL2 = (role == 3);
    const uint4* wpk = isL2 ? wpk1 : wpk0;
    const _Float16* gxr = isL2 ? gx2r : gx1r;
    float* hst = isL2 ? hs2 : hs1;
    float* cst = isL2 ? cs2 : cs1;
    Line* fIn  = isL2 ? fG2 : fG1;
    Line* fOut = isL2 ? fL2 : fL1;
    const int b = sub;
    const int tau = tid;                 // one unit per thread

    // stage LDS weight slices: k2 in [96,128)
#pragma unroll
    for (int m = 0; m < 32; m++)
        wl[m * 256 + tau] = wpk[(size_t)(96 + m) * 256 + tau];

    // 96 volatile-resident quads: k2 in [0,96)
    uint4 w4[96];
    {
        const volatile unsigned* wv = (const volatile unsigned*)wpk;
#pragma unroll
        for (int r = 0; r < 96; r++) {
            size_t base = ((size_t)r * 256 + tau) * 4;
            w4[r].x = wv[base + 0];
            w4[r].y = wv[base + 1];
            w4[r].z = wv[base + 2];
            w4[r].w = wv[base + 3];
        }
    }

    float c_ = cst[b * HH + tau];
    float lastH = hst[b * HH + tau];
    hlb[tau] = (_Float16)lastH;
    __syncthreads();

    int p = 0;
    for (int ch = 0; ch < NCH; ch++) {
        wait_flags(fIn, (unsigned)(ch + 1), tid);
        const _Float16* gsl = gxr + (size_t)(ch % NR) * CH * BB * H4
                            + (size_t)b * H4 + tau * 4;
        uint2 gq = *(const uint2*)gsl;

        for (int l = 0; l < CH; l++) {
            uint2 gqn = gq;
            if (l < CH - 1)
                gqn = *(const uint2*)(gsl + (size_t)(l + 1) * BB * H4);

            const uint4* hp4 = (const uint4*)(hlb + p * 272);   // 32 quads
            float a0 = 0.f, a1 = 0.f, a2 = 0.f, a3 = 0.f;

            // register tier: k2 = 4j+u for j in [0,24)
#pragma unroll
            for (int j = 0; j < 24; j++) {
                uint4 hq = hp4[j];
#pragma unroll
                for (int u = 0; u < 4; u++) {
                    half2v hv = __builtin_bit_cast(half2v, hq[u]);
                    uint4 w = w4[4 * j + u];
                    a0 = fdot2_(w.x, hv, a0);
                    a1 = fdot2_(w.y, hv, a1);
                    a2 = fdot2_(w.z, hv, a2);
                    a3 = fdot2_(w.w, hv, a3);
                }
            }
            // LDS tier: k2 in [96,128) -> slice 4(j-24)+u
#pragma unroll
            for (int j = 24; j < 32; j++) {
                uint4 hq = hp4[j];
#pragma unroll
                for (int u = 0; u < 4; u++) {
                    uint4 w = wl[(4 * (j - 24) + u) * 256 + tau];
                    half2v hv = __builtin_bit_cast(half2v, hq[u]);
                    a0 = fdot2_(w.x, hv, a0);
                    a1 = fdot2_(w.y, hv, a1);
                    a2 = fdot2_(w.z, hv, a2);
                    a3 = fdot2_(w.w, hv, a3);
                }
            }

            // gates (fully parallel; gx gate-interleaved: i,f | g,o)
            half2v glo = __builtin_bit_cast(half2v, gq.x);
            half2v ghi = __builtin_bit_cast(half2v, gq.y);
            float ig = fsig_(a0 + (float)glo[0]);
            float fg = fsig_(a1 + (float)glo[1]);
            float gg = ftanh_(a2 + (float)ghi[0]);
            float og = fsig_(a3 + (float)ghi[1]);
            c_ = fg * c_ + ig * gg;
            float h = og * ftanh_(c_);
            lastH = h;
            if (!isL2)
                h1c[((size_t)b * TT + ch * CH + l) * HH + tau] = (_Float16)h;
            hlb[(p ^ 1) * 272 + tau] = (_Float16)h;
            __syncthreads();            // the ONE barrier per step
            p ^= 1;
            gq = gqn;
        }

        if (tid == 0) {
            if (!isL2) __builtin_amdgcn_fence(__ATOMIC_RELEASE, "agent");
            __hip_atomic_store(&fOut[b].v, (unsigned)(ch + 1),
                               __ATOMIC_RELAXED, __HIP_MEMORY_SCOPE_AGENT);
        }
    }

    cst[b * HH + tau] = c_;
    hst[b * HH + tau] = lastH;
}

// ---------------------------------------------------------------------------
__global__ void fc_kernel(const float* __restrict__ h2,
                          const float* __restrict__ Wfc,
                          const float* __restrict__ bfc,
                          float* __restrict__ out)
{
    __shared__ float hs[256];
    int b = blockIdx.x, tid = threadIdx.x;
    hs[tid] = h2[b * HH + tid];
    __syncthreads();
    if (tid < NC) {
        float s = bfc[tid];
        for (int k = 0; k < 256; k++) s += hs[k] * Wfc[tid * 256 + k];
        out[b * NC + tid] = s;
    }
}

// ---------------------------------------------------------------------------
extern "C" void kernel_launch(void* const* d_in, const int* in_sizes, int n_in,
                              void* d_out, int out_size, void* d_ws, size_t ws_size,
                              hipStream_t stream)
{
    const float* x    = (const float*)d_in[0];
    const float* Wih0 = (const float*)d_in[1];
    const float* Whh0 = (const float*)d_in[2];
    const float* bih0 = (const float*)d_in[3];
    const float* bhh0 = (const float*)d_in[4];
    const float* Wih1 = (const float*)d_in[5];
    const float* Whh1 = (const float*)d_in[6];
    const float* bih1 = (const float*)d_in[7];
    const float* bhh1 = (const float*)d_in[8];
    const float* Wfc  = (const float*)d_in[9];
    const float* bfc  = (const float*)d_in[10];

    const size_t x16_b  = (size_t)BB * TT * HH * 2;      // 67.1 MB
    const size_t h1c_b  = x16_b;                          // 67.1 MB
    const size_t gxr_b  = (size_t)NR * CH * BB * H4 * 2;  // 16.8 MB
    const size_t w16_b  = (size_t)H4 * HH * 2;
    const size_t wpk_b  = (size_t)128 * 256 * 16;
    const size_t st_b   = (size_t)4 * BB * HH * 4;

    char* pp = (char*)d_ws;
    _Float16* x16  = (_Float16*)pp;  pp += x16_b;
    _Float16* h1c  = (_Float16*)pp;  pp += h1c_b;
    _Float16* gx1r = (_Float16*)pp;  pp += gxr_b;
    _Float16* gx2r = (_Float16*)pp;  pp += gxr_b;
    _Float16* w16a = (_Float16*)pp;  pp += w16_b;
    _Float16* w16b = (_Float16*)pp;  pp += w16_b;
    uint4*    wpk0 = (uint4*)pp;     pp += wpk_b;
    uint4*    wpk1 = (uint4*)pp;     pp += wpk_b;
    float*    hs1  = (float*)pp;
    float*    cs1  = hs1 + BB * HH;
    float*    hs2  = cs1 + BB * HH;
    float*    cs2  = hs2 + BB * HH;
    pp += st_b;
    Line* fG1 = (Line*)pp;
    Line* fL1 = fG1 + 64;
    Line* fG2 = fL1 + 64;
    Line* fL2 = fG2 + 64;

    // zero states + flags (contiguous)
    hipMemsetAsync(hs1, 0, st_b + 256 * sizeof(Line), stream);

    prep_w<<<128, 256, 0, stream>>>(Whh0, wpk0);
    prep_w<<<128, 256, 0, stream>>>(Whh1, wpk1);
    f32_to_f16<<<(BB * TT * HH / 8 + 255) / 256, 256, 0, stream>>>(x, x16, BB * TT * HH / 8);
    f32_to_f16<<<(H4 * HH / 8 + 255) / 256, 256, 0, stream>>>(Wih0, w16a, H4 * HH / 8);
    f32_to_f16<<<(H4 * HH / 8 + 255) / 256, 256, 0, stream>>>(Wih1, w16b, H4 * HH / 8);

    lstm_pipe<<<256, 256, 0, stream>>>(x16, w16a, w16b,
                                       bih0, bhh0, bih1, bhh1,
                                       wpk0, wpk1, gx1r, gx2r, h1c,
                                       hs1, cs1, hs2, cs2,
                                       fG1, fL1, fG2, fL2);

    fc_kernel<<<BB, 256, 0, stream>>>(hs2, Wfc, bfc, (float*)d_out);
}

// Round 19
// 3700.773 us; speedup vs baseline: 1.8843x; 1.8843x over previous
//
#include <hip/hip_runtime.h>
#include <hip/hip_bf16.h>

#define BB 64
#define TT 2048
#define HH 256
#define H4 1024
#define NC 10
#define CH 32            // steps per chunk
#define NCH (TT / CH)    // 64 chunks
#define NR 4             // gx ring slots

typedef _Float16 half2v __attribute__((ext_vector_type(2)));
typedef _Float16 half8  __attribute__((ext_vector_type(8)));
typedef float    f32x4  __attribute__((ext_vector_type(4)));

struct __align__(128) Line { unsigned v; unsigned pad[31]; };

__device__ __forceinline__ float fsig_(float x) {
    return __fdividef(1.f, 1.f + __expf(-x));
}
__device__ __forceinline__ float ftanh_(float x) {
    return 1.f - __fdividef(2.f, __expf(2.f * x) + 1.f);
}

__device__ __forceinline__ float fdot2_(unsigned wu, half2v hv, float acc) {
#if __has_builtin(__builtin_amdgcn_fdot2)
    return __builtin_amdgcn_fdot2(__builtin_bit_cast(half2v, wu), hv, acc, false);
#else
    half2v w = __builtin_bit_cast(half2v, wu);
    return acc + (float)w[0] * (float)hv[0] + (float)w[1] * (float)hv[1];
#endif
}

// wave-0 parallel poll of 64 flags; one acquire fence; releases whole WG.
__device__ __forceinline__ void wait_flags(Line* f, unsigned target, int tid) {
    if (tid < 64) {
        while (true) {
            unsigned v = __hip_atomic_load(&f[tid].v, __ATOMIC_RELAXED,
                                           __HIP_MEMORY_SCOPE_AGENT);
            if (__all(v >= target)) break;
            __builtin_amdgcn_s_sleep(2);
        }
        if (tid == 0)
            __builtin_amdgcn_fence(__ATOMIC_ACQUIRE, "agent");
    }
    __syncthreads();
}

// ---------------------------------------------------------------------------
__global__ void f32_to_f16(const float* __restrict__ in,
                           _Float16* __restrict__ out, int n8)
{
    int i = blockIdx.x * 256 + threadIdx.x;
    if (i >= n8) return;
    float4 v0 = ((const float4*)in)[2 * i];
    float4 v1 = ((const float4*)in)[2 * i + 1];
    half8 h;
    h[0] = (_Float16)v0.x; h[1] = (_Float16)v0.y;
    h[2] = (_Float16)v0.z; h[3] = (_Float16)v0.w;
    h[4] = (_Float16)v1.x; h[5] = (_Float16)v1.y;
    h[6] = (_Float16)v1.z; h[7] = (_Float16)v1.w;
    ((half8*)out)[i] = h;
}

// ---------------------------------------------------------------------------
__global__ void prep_w(const float* __restrict__ W, uint4* __restrict__ out)
{
    const int k2 = blockIdx.x, t = threadIdx.x;
    unsigned q4[4];
#pragma unroll
    for (int q = 0; q < 4; q++) {
        const float* wr = W + (size_t)(q * 256 + t) * 256 + 2 * k2;
        union { _Float16 h[2]; unsigned u; } cv;
        cv.h[0] = (_Float16)wr[0];
        cv.h[1] = (_Float16)wr[1];
        q4[q] = cv.u;
    }
    out[(size_t)k2 * 256 + t] = make_uint4(q4[0], q4[1], q4[2], q4[3]);
}

// ---------------------------------------------------------------------------
// 4-role pipelined persistent kernel, 256 WGs x 512 threads (R17 topology).
// REC engine v2: INTRA-WAVE k-split. Wave w lane l: unit tau = w*32+(l&31),
// half hh = l>>5. Partial exchange via shfl_xor(32) -> no pre[] LDS, no
// exchange barrier; gates computed redundantly in both lanes (parallel);
// ONE barrier per step (double-buffered hlb). Weight tiers as R17:
// 48 resident quads (volatile, AGPR-backed) + 16 LDS slices per half.
// ---------------------------------------------------------------------------
__global__ __launch_bounds__(512, 1)
void lstm_pipe(const _Float16* __restrict__ x16,
               const _Float16* __restrict__ w16a, const _Float16* __restrict__ w16b,
               const float* __restrict__ bih0, const float* __restrict__ bhh0,
               const float* __restrict__ bih1, const float* __restrict__ bhh1,
               const uint4* __restrict__ wpk0, const uint4* __restrict__ wpk1,
               _Float16* __restrict__ gx1r, _Float16* __restrict__ gx2r,
               _Float16* __restrict__ h1c,
               float* __restrict__ hs1, float* __restrict__ cs1,
               float* __restrict__ hs2, float* __restrict__ cs2,
               Line* __restrict__ fG1, Line* __restrict__ fL1,
               Line* __restrict__ fG2, Line* __restrict__ fL2)
{
    __shared__ __align__(16) unsigned char pool[1088 + 32 * 4096];
    _Float16* hlb = (_Float16*)pool;              // [2][272] halves
    uint4*    wl  = (uint4*)(pool + 1088);        // [32][256] quads (128 KB)

    const int wg = blockIdx.x, tid = threadIdx.x;
    const int role = wg >> 6, sub = wg & 63;

    if (role == 1 || role == 2) {
        // ---------------- gemm worker (identical to R17) ----------------
        const bool isG2 = (role == 2);
        const _Float16* A  = isG2 ? h1c  : x16;
        const _Float16* Wm = isG2 ? w16b : w16a;
        const float* b1 = isG2 ? bih1 : bih0;
        const float* b2 = isG2 ? bhh1 : bhh0;
        _Float16* outr  = isG2 ? gx2r : gx1r;
        Line* fOut      = isG2 ? fG2  : fG1;

        const int v = tid >> 6, lane = tid & 63;
        const int lrow = lane & 15, lkg = lane >> 4;
        const int rquad = v & 3, nqh = v >> 2;
        const int tcl = sub & 31;
        const int n0 = (sub >> 5) * 512 + nqh * 256;

        const _Float16* wrow0 = Wm + (size_t)(n0 + lrow) * 256 + lkg * 8;

        for (int c = 0; c < NCH; c++) {
            if (isG2) {
                wait_flags(fL1, (unsigned)(c + 1), tid);
                if (c >= NR) wait_flags(fL2, (unsigned)(c - (NR - 1)), tid);
            } else {
                if (c >= NR) wait_flags(fL1, (unsigned)(c - (NR - 1)), tid);
            }
            const int tc = c * CH + tcl;
            const int slot = c % NR;
            const _Float16* arow =
                A + ((size_t)(rquad * 16 + lrow) * TT + tc) * 256 + lkg * 8;

            f32x4 acc[16];
#pragma unroll
            for (int j = 0; j < 16; j++) acc[j] = (f32x4)(0.f);
#pragma unroll
            for (int k0 = 0; k0 < 256; k0 += 32) {
                half8 a = *(const half8*)(arow + k0);
#pragma unroll
                for (int j = 0; j < 16; j++) {
                    half8 bf = *(const half8*)(wrow0 + (size_t)j * 16 * 256 + k0);
                    acc[j] = __builtin_amdgcn_mfma_f32_16x16x32_f16(a, bf, acc[j], 0, 0, 0);
                }
            }
            const int bout = rquad * 16 + lkg * 4;
#pragma unroll
            for (int j = 0; j < 16; j++) {
                int n = n0 + j * 16 + lrow;
                float bsum = b1[n] + b2[n];
                int u = n & 255, q = n >> 8;       // gate-interleaved target
#pragma unroll
                for (int r = 0; r < 4; r++) {
                    outr[((size_t)(slot * CH + tcl) * BB + bout + r) * H4 + u * 4 + q] =
                        (_Float16)(acc[j][r] + bsum);
                }
            }
            __syncthreads();
            if (tid == 0) {
                __builtin_amdgcn_fence(__ATOMIC_RELEASE, "agent");
                __hip_atomic_store(&fOut[sub].v, (unsigned)(c + 1),
                                   __ATOMIC_RELAXED, __HIP_MEMORY_SCOPE_AGENT);
            }
        }
        return;
    }

    // ---------------- recurrence (role 0 = L1, role 3 = L2) ----------------
    const bool isL2 = (role == 3);
    const uint4* wpk = isL2 ? wpk1 : wpk0;
    const _Float16* gxr = isL2 ? gx2r : gx1r;
    float* hst = isL2 ? hs2 : hs1;
    float* cst = isL2 ? cs2 : cs1;
    Line* fIn  = isL2 ? fG2 : fG1;
    Line* fOut = isL2 ? fL2 : fL1;
    const int b = sub;
    const int w = tid >> 6, lane = tid & 63;
    const int tau = w * 32 + (lane & 31);     // unit
    const int hh  = lane >> 5;                // k-half (intra-wave!)

    // stage LDS weight slices: s in [0,16) -> k2 48+s (hh0), [16,32) -> 96+s (hh1)
#pragma unroll
    for (int m = 0; m < 16; m++) {
        int e = m * 512 + tid;
        int s = e >> 8, tp = e & 255;
        int k2g = (s < 16) ? (48 + s) : (96 + s);
        wl[e] = wpk[(size_t)k2g * 256 + tp];
    }

    // 48 resident quads: k2 = hh*64 + r (volatile: exactly-once, AGPR-backed)
    uint4 w4[48];
    {
        const volatile unsigned* wv = (const volatile unsigned*)wpk;
#pragma unroll
        for (int r = 0; r < 48; r++) {
            size_t base = ((size_t)(hh * 64 + r) * 256 + tau) * 4;
            w4[r].x = wv[base + 0];
            w4[r].y = wv[base + 1];
            w4[r].z = wv[base + 2];
            w4[r].w = wv[base + 3];
        }
    }

    const uint4* wbase = wl + hh * 4096 + tau;

    // state duplicated in both lanes (identical deterministic computation)
    float c_ = cst[b * HH + tau];
    float lastH = hst[b * HH + tau];
    if (hh == 0) hlb[tau] = (_Float16)lastH;
    __syncthreads();

    int p = 0;
    for (int ch = 0; ch < NCH; ch++) {
        wait_flags(fIn, (unsigned)(ch + 1), tid);
        const _Float16* gsl = gxr + (size_t)(ch % NR) * CH * BB * H4
                            + (size_t)b * H4 + tau * 4;
        uint2 gq = *(const uint2*)gsl;          // both halves load (same addr)

        for (int l = 0; l < CH; l++) {
            uint2 gqn = gq;
            if (l < CH - 1)
                gqn = *(const uint2*)(gsl + (size_t)(l + 1) * BB * H4);

            const uint4* hp4 = (const uint4*)(hlb + p * 272) + hh * 16;
            float a0 = 0.f, a1 = 0.f, a2 = 0.f, a3 = 0.f;

            // register tier: r = 4j+u, j in [0,12)
#pragma unroll
            for (int j = 0; j < 12; j++) {
                uint4 hq = hp4[j];
#pragma unroll
                for (int u = 0; u < 4; u++) {
                    half2v hv = __builtin_bit_cast(half2v, hq[u]);
                    uint4 ww = w4[4 * j + u];
                    a0 = fdot2_(ww.x, hv, a0);
                    a1 = fdot2_(ww.y, hv, a1);
                    a2 = fdot2_(ww.z, hv, a2);
                    a3 = fdot2_(ww.w, hv, a3);
                }
            }
            // LDS tier: j in [12,16)
#pragma unroll
            for (int j = 12; j < 16; j++) {
                uint4 hq = hp4[j];
#pragma unroll
                for (int u = 0; u < 4; u++) {
                    uint4 ww = wbase[(4 * (j - 12) + u) * 256];
                    half2v hv = __builtin_bit_cast(half2v, hq[u]);
                    a0 = fdot2_(ww.x, hv, a0);
                    a1 = fdot2_(ww.y, hv, a1);
                    a2 = fdot2_(ww.z, hv, a2);
                    a3 = fdot2_(ww.w, hv, a3);
                }
            }

            // intra-wave partial exchange: lane l <-> lane l^32 (no barrier)
            a0 += __shfl_xor(a0, 32, 64);
            a1 += __shfl_xor(a1, 32, 64);
            a2 += __shfl_xor(a2, 32, 64);
            a3 += __shfl_xor(a3, 32, 64);

            // gates: both lanes compute (redundant, parallel, identical)
            half2v glo = __builtin_bit_cast(half2v, gq.x);
            half2v ghi = __builtin_bit_cast(half2v, gq.y);
            float ig = fsig_(a0 + (float)glo[0]);
            float fg = fsig_(a1 + (float)glo[1]);
            float gg = ftanh_(a2 + (float)ghi[0]);
            float og = fsig_(a3 + (float)ghi[1]);
            c_ = fg * c_ + ig * gg;
            float h = og * ftanh_(c_);
            lastH = h;
            if (hh == 0) {
                if (!isL2)
                    h1c[((size_t)b * TT + ch * CH + l) * HH + tau] = (_Float16)h;
                hlb[(p ^ 1) * 272 + tau] = (_Float16)h;
            }
            __syncthreads();            // the ONE barrier per step
            p ^= 1;
            gq = gqn;
        }

        if (tid == 0) {
            if (!isL2) __builtin_amdgcn_fence(__ATOMIC_RELEASE, "agent");
            __hip_atomic_store(&fOut[b].v, (unsigned)(ch + 1),
                               __ATOMIC_RELAXED, __HIP_MEMORY_SCOPE_AGENT);
        }
    }

    if (hh == 0) {
        cst[b * HH + tau] = c_;
        hst[b * HH + tau] = lastH;
    }
}

// ---------------------------------------------------------------------------
__global__ void fc_kernel(const float* __restrict__ h2,
                          const float* __restrict__ Wfc,
                          const float* __restrict__ bfc,
                          float* __restrict__ out)
{
    __shared__ float hs[256];
    int b = blockIdx.x, tid = threadIdx.x;
    hs[tid] = h2[b * HH + tid];
    __syncthreads();
    if (tid < NC) {
        float s = bfc[tid];
        for (int k = 0; k < 256; k++) s += hs[k] * Wfc[tid * 256 + k];
        out[b * NC + tid] = s;
    }
}

// ---------------------------------------------------------------------------
extern "C" void kernel_launch(void* const* d_in, const int* in_sizes, int n_in,
                              void* d_out, int out_size, void* d_ws, size_t ws_size,
                              hipStream_t stream)
{
    const float* x    = (const float*)d_in[0];
    const float* Wih0 = (const float*)d_in[1];
    const float* Whh0 = (const float*)d_in[2];
    const float* bih0 = (const float*)d_in[3];
    const float* bhh0 = (const float*)d_in[4];
    const float* Wih1 = (const float*)d_in[5];
    const float* Whh1 = (const float*)d_in[6];
    const float* bih1 = (const float*)d_in[7];
    const float* bhh1 = (const float*)d_in[8];
    const float* Wfc  = (const float*)d_in[9];
    const float* bfc  = (const float*)d_in[10];

    const size_t x16_b  = (size_t)BB * TT * HH * 2;      // 67.1 MB
    const size_t h1c_b  = x16_b;                          // 67.1 MB
    const size_t gxr_b  = (size_t)NR * CH * BB * H4 * 2;  // 16.8 MB
    const size_t w16_b  = (size_t)H4 * HH * 2;
    const size_t wpk_b  = (size_t)128 * 256 * 16;
    const size_t st_b   = (size_t)4 * BB * HH * 4;

    char* pp = (char*)d_ws;
    _Float16* x16  = (_Float16*)pp;  pp += x16_b;
    _Float16* h1c  = (_Float16*)pp;  pp += h1c_b;
    _Float16* gx1r = (_Float16*)pp;  pp += gxr_b;
    _Float16* gx2r = (_Float16*)pp;  pp += gxr_b;
    _Float16* w16a = (_Float16*)pp;  pp += w16_b;
    _Float16* w16b = (_Float16*)pp;  pp += w16_b;
    uint4*    wpk0 = (uint4*)pp;     pp += wpk_b;
    uint4*    wpk1 = (uint4*)pp;     pp += wpk_b;
    float*    hs1  = (float*)pp;
    float*    cs1  = hs1 + BB * HH;
    float*    hs2  = cs1 + BB * HH;
    float*    cs2  = hs2 + BB * HH;
    pp += st_b;
    Line* fG1 = (Line*)pp;
    Line* fL1 = fG1 + 64;
    Line* fG2 = fL1 + 64;
    Line* fL2 = fG2 + 64;

    // zero states + flags (contiguous)
    hipMemsetAsync(hs1, 0, st_b + 256 * sizeof(Line), stream);

    prep_w<<<128, 256, 0, stream>>>(Whh0, wpk0);
    prep_w<<<128, 256, 0, stream>>>(Whh1, wpk1);
    f32_to_f16<<<(BB * TT * HH / 8 + 255) / 256, 256, 0, stream>>>(x, x16, BB * TT * HH / 8);
    f32_to_f16<<<(H4 * HH / 8 + 255) / 256, 256, 0, stream>>>(Wih0, w16a, H4 * HH / 8);
    f32_to_f16<<<(H4 * HH / 8 + 255) / 256, 256, 0, stream>>>(Wih1, w16b, H4 * HH / 8);

    lstm_pipe<<<256, 512, 0, stream>>>(x16, w16a, w16b,
                                       bih0, bhh0, bih1, bhh1,
                                       wpk0, wpk1, gx1r, gx2r, h1c,
                                       hs1, cs1, hs2, cs2,
                                       fG1, fL1, fG2, fL2);

    fc_kernel<<<BB, 256, 0, stream>>>(hs2, Wfc, bfc, (float*)d_out);
}

// Round 21
// 3671.756 us; speedup vs baseline: 1.8991x; 1.0079x over previous
//
#include <hip/hip_runtime.h>
#include <hip/hip_bf16.h>

#define BB 64
#define TT 2048
#define HH 256
#define H4 1024
#define NC 10
#define CH 32            // steps per chunk
#define NCH (TT / CH)    // 64 chunks
#define NR 4             // gx ring slots

typedef _Float16 half2v __attribute__((ext_vector_type(2)));
typedef _Float16 half8  __attribute__((ext_vector_type(8)));
typedef float    f32x4  __attribute__((ext_vector_type(4)));

struct __align__(128) Line { unsigned v; unsigned pad[31]; };

__device__ __forceinline__ float fsig_(float x) {
    return __fdividef(1.f, 1.f + __expf(-x));
}
__device__ __forceinline__ float ftanh_(float x) {
    return 1.f - __fdividef(2.f, __expf(2.f * x) + 1.f);
}

__device__ __forceinline__ float fdot2_(unsigned wu, half2v hv, float acc) {
#if __has_builtin(__builtin_amdgcn_fdot2)
    return __builtin_amdgcn_fdot2(__builtin_bit_cast(half2v, wu), hv, acc, false);
#else
    half2v w = __builtin_bit_cast(half2v, wu);
    return acc + (float)w[0] * (float)hv[0] + (float)w[1] * (float)hv[1];
#endif
}

// pair sum via DPP quad_perm [1,0,3,2] (dpp_ctrl 0xB1): lane gets own + lane^1.
// Pure VALU, gfx8-era fixed semantics — no LDS unit, no permlane aliasing trap.
__device__ __forceinline__ float xpair_sum_(float a) {
    int ai = __builtin_bit_cast(int, a);
    int bi = __builtin_amdgcn_mov_dpp(ai, 0xB1, 0xF, 0xF, true);
    return a + __builtin_bit_cast(float, bi);
}

// wave-0 parallel poll of 64 flags; one acquire fence; releases whole WG.
__device__ __forceinline__ void wait_flags(Line* f, unsigned target, int tid) {
    if (tid < 64) {
        while (true) {
            unsigned v = __hip_atomic_load(&f[tid].v, __ATOMIC_RELAXED,
                                           __HIP_MEMORY_SCOPE_AGENT);
            if (__all(v >= target)) break;
            __builtin_amdgcn_s_sleep(2);
        }
        if (tid == 0)
            __builtin_amdgcn_fence(__ATOMIC_ACQUIRE, "agent");
    }
    __syncthreads();
}

// ---------------------------------------------------------------------------
__global__ void f32_to_f16(const float* __restrict__ in,
                           _Float16* __restrict__ out, int n8)
{
    int i = blockIdx.x * 256 + threadIdx.x;
    if (i >= n8) return;
    float4 v0 = ((const float4*)in)[2 * i];
    float4 v1 = ((const float4*)in)[2 * i + 1];
    half8 h;
    h[0] = (_Float16)v0.x; h[1] = (_Float16)v0.y;
    h[2] = (_Float16)v0.z; h[3] = (_Float16)v0.w;
    h[4] = (_Float16)v1.x; h[5] = (_Float16)v1.y;
    h[6] = (_Float16)v1.z; h[7] = (_Float16)v1.w;
    ((half8*)out)[i] = h;
}

// ---------------------------------------------------------------------------
__global__ void prep_w(const float* __restrict__ W, uint4* __restrict__ out)
{
    const int k2 = blockIdx.x, t = threadIdx.x;
    unsigned q4[4];
#pragma unroll
    for (int q = 0; q < 4; q++) {
        const float* wr = W + (size_t)(q * 256 + t) * 256 + 2 * k2;
        union { _Float16 h[2]; unsigned u; } cv;
        cv.h[0] = (_Float16)wr[0];
        cv.h[1] = (_Float16)wr[1];
        q4[q] = cv.u;
    }
    out[(size_t)k2 * 256 + t] = make_uint4(q4[0], q4[1], q4[2], q4[3]);
}

// ---------------------------------------------------------------------------
// 4-role pipelined persistent kernel, 256 WGs x 512 threads (R17 topology).
// REC engine v4: INTRA-WAVE k-split on lane bit 0.
// Wave w lane l: unit tau = w*32 + (l>>1), half hh = l&1.
// Partial exchange = 4x (mov_dpp quad_perm + add) — pure VALU, exact.
// One barrier per step; gates redundant in lane pairs; weights: 48 resident
// quads (volatile/AGPR) + 16 LDS slices per half. gx gate-interleaved.
// (R19: shfl_xor(32) -> ds_bpermute, slow. R20: permlane32_swap aliasing
//  trap -> wrong. DPP lane^1 has neither problem.)
// ---------------------------------------------------------------------------
__global__ __launch_bounds__(512, 1)
void lstm_pipe(const _Float16* __restrict__ x16,
               const _Float16* __restrict__ w16a, const _Float16* __restrict__ w16b,
               const float* __restrict__ bih0, const float* __restrict__ bhh0,
               const float* __restrict__ bih1, const float* __restrict__ bhh1,
               const uint4* __restrict__ wpk0, const uint4* __restrict__ wpk1,
               _Float16* __restrict__ gx1r, _Float16* __restrict__ gx2r,
               _Float16* __restrict__ h1c,
               float* __restrict__ hs1, float* __restrict__ cs1,
               float* __restrict__ hs2, float* __restrict__ cs2,
               Line* __restrict__ fG1, Line* __restrict__ fL1,
               Line* __restrict__ fG2, Line* __restrict__ fL2)
{
    __shared__ __align__(16) unsigned char pool[1088 + 32 * 4096];
    _Float16* hlb = (_Float16*)pool;              // [2][272] halves
    uint4*    wl  = (uint4*)(pool + 1088);        // [32][256] quads (128 KB)

    const int wg = blockIdx.x, tid = threadIdx.x;
    const int role = wg >> 6, sub = wg & 63;

    if (role == 1 || role == 2) {
        // ---------------- gemm worker (identical to R17) ----------------
        const bool isG2 = (role == 2);
        const _Float16* A  = isG2 ? h1c  : x16;
        const _Float16* Wm = isG2 ? w16b : w16a;
        const float* b1 = isG2 ? bih1 : bih0;
        const float* b2 = isG2 ? bhh1 : bhh0;
        _Float16* outr  = isG2 ? gx2r : gx1r;
        Line* fOut      = isG2 ? fG2  : fG1;

        const int v = tid >> 6, lane = tid & 63;
        const int lrow = lane & 15, lkg = lane >> 4;
        const int rquad = v & 3, nqh = v >> 2;
        const int tcl = sub & 31;
        const int n0 = (sub >> 5) * 512 + nqh * 256;

        const _Float16* wrow0 = Wm + (size_t)(n0 + lrow) * 256 + lkg * 8;

        for (int c = 0; c < NCH; c++) {
            if (isG2) {
                wait_flags(fL1, (unsigned)(c + 1), tid);
                if (c >= NR) wait_flags(fL2, (unsigned)(c - (NR - 1)), tid);
            } else {
                if (c >= NR) wait_flags(fL1, (unsigned)(c - (NR - 1)), tid);
            }
            const int tc = c * CH + tcl;
            const int slot = c % NR;
            const _Float16* arow =
                A + ((size_t)(rquad * 16 + lrow) * TT + tc) * 256 + lkg * 8;

            f32x4 acc[16];
#pragma unroll
            for (int j = 0; j < 16; j++) acc[j] = (f32x4)(0.f);
#pragma unroll
            for (int k0 = 0; k0 < 256; k0 += 32) {
                half8 a = *(const half8*)(arow + k0);
#pragma unroll
                for (int j = 0; j < 16; j++) {
                    half8 bf = *(const half8*)(wrow0 + (size_t)j * 16 * 256 + k0);
                    acc[j] = __builtin_amdgcn_mfma_f32_16x16x32_f16(a, bf, acc[j], 0, 0, 0);
                }
            }
            const int bout = rquad * 16 + lkg * 4;
#pragma unroll
            for (int j = 0; j < 16; j++) {
                int n = n0 + j * 16 + lrow;
                float bsum = b1[n] + b2[n];
                int u = n & 255, q = n >> 8;       // gate-interleaved target
#pragma unroll
                for (int r = 0; r < 4; r++) {
                    outr[((size_t)(slot * CH + tcl) * BB + bout + r) * H4 + u * 4 + q] =
                        (_Float16)(acc[j][r] + bsum);
                }
            }
            __syncthreads();
            if (tid == 0) {
                __builtin_amdgcn_fence(__ATOMIC_RELEASE, "agent");
                __hip_atomic_store(&fOut[sub].v, (unsigned)(c + 1),
                                   __ATOMIC_RELAXED, __HIP_MEMORY_SCOPE_AGENT);
            }
        }
        return;
    }

    // ---------------- recurrence (role 0 = L1, role 3 = L2) ----------------
    const bool isL2 = (role == 3);
    const uint4* wpk = isL2 ? wpk1 : wpk0;
    const _Float16* gxr = isL2 ? gx2r : gx1r;
    float* hst = isL2 ? hs2 : hs1;
    float* cst = isL2 ? cs2 : cs1;
    Line* fIn  = isL2 ? fG2 : fG1;
    Line* fOut = isL2 ? fL2 : fL1;
    const int b = sub;
    const int w = tid >> 6, lane = tid & 63;
    const int tau = w * 32 + (lane >> 1);     // unit
    const int hh  = lane & 1;                 // k-half (pairwise intra-wave)

    // stage LDS weight slices: s in [0,16) -> k2 48+s (hh0), [16,32) -> 96+s (hh1)
#pragma unroll
    for (int m = 0; m < 16; m++) {
        int e = m * 512 + tid;
        int s = e >> 8, tp = e & 255;
        int k2g = (s < 16) ? (48 + s) : (96 + s);
        wl[e] = wpk[(size_t)k2g * 256 + tp];
    }

    // 48 resident quads: k2 = hh*64 + r (volatile: exactly-once, AGPR-backed)
    uint4 w4[48];
    {
        const volatile unsigned* wv = (const volatile unsigned*)wpk;
#pragma unroll
        for (int r = 0; r < 48; r++) {
            size_t base = ((size_t)(hh * 64 + r) * 256 + tau) * 4;
            w4[r].x = wv[base + 0];
            w4[r].y = wv[base + 1];
            w4[r].z = wv[base + 2];
            w4[r].w = wv[base + 3];
        }
    }

    const uint4* wbase = wl + hh * 4096 + tau;

    // state duplicated in both lanes of a pair (identical computation)
    float c_ = cst[b * HH + tau];
    float lastH = hst[b * HH + tau];
    if (hh == 0) hlb[tau] = (_Float16)lastH;
    __syncthreads();

    int p = 0;
    for (int ch = 0; ch < NCH; ch++) {
        wait_flags(fIn, (unsigned)(ch + 1), tid);
        const _Float16* gsl = gxr + (size_t)(ch % NR) * CH * BB * H4
                            + (size_t)b * H4 + tau * 4;
        uint2 gq = *(const uint2*)gsl;          // both pair-lanes load (same addr)

        for (int l = 0; l < CH; l++) {
            uint2 gqn = gq;
            if (l < CH - 1)
                gqn = *(const uint2*)(gsl + (size_t)(l + 1) * BB * H4);

            const uint4* hp4 = (const uint4*)(hlb + p * 272) + hh * 16;
            float a0 = 0.f, a1 = 0.f, a2 = 0.f, a3 = 0.f;

            // register tier: r = 4j+u, j in [0,12)
#pragma unroll
            for (int j = 0; j < 12; j++) {
                uint4 hq = hp4[j];
#pragma unroll
                for (int u = 0; u < 4; u++) {
                    half2v hv = __builtin_bit_cast(half2v, hq[u]);
                    uint4 ww = w4[4 * j + u];
                    a0 = fdot2_(ww.x, hv, a0);
                    a1 = fdot2_(ww.y, hv, a1);
                    a2 = fdot2_(ww.z, hv, a2);
                    a3 = fdot2_(ww.w, hv, a3);
                }
            }
            // LDS tier: j in [12,16)
#pragma unroll
            for (int j = 12; j < 16; j++) {
                uint4 hq = hp4[j];
#pragma unroll
                for (int u = 0; u < 4; u++) {
                    uint4 ww = wbase[(4 * (j - 12) + u) * 256];
                    half2v hv = __builtin_bit_cast(half2v, hq[u]);
                    a0 = fdot2_(ww.x, hv, a0);
                    a1 = fdot2_(ww.y, hv, a1);
                    a2 = fdot2_(ww.z, hv, a2);
                    a3 = fdot2_(ww.w, hv, a3);
                }
            }

            // pairwise partial exchange: DPP quad_perm + add (pure VALU)
            a0 = xpair_sum_(a0);
            a1 = xpair_sum_(a1);
            a2 = xpair_sum_(a2);
            a3 = xpair_sum_(a3);

            // gates: both pair-lanes compute (redundant, parallel, identical)
            half2v glo = __builtin_bit_cast(half2v, gq.x);
            half2v ghi = __builtin_bit_cast(half2v, gq.y);
            float ig = fsig_(a0 + (float)glo[0]);
            float fg = fsig_(a1 + (float)glo[1]);
            float gg = ftanh_(a2 + (float)ghi[0]);
            float og = fsig_(a3 + (float)ghi[1]);
            c_ = fg * c_ + ig * gg;
            float h = og * ftanh_(c_);
            lastH = h;
            if (hh == 0) {
                if (!isL2)
                    h1c[((size_t)b * TT + ch * CH + l) * HH + tau] = (_Float16)h;
                hlb[(p ^ 1) * 272 + tau] = (_Float16)h;
            }
            __syncthreads();            // the ONE barrier per step
            p ^= 1;
            gq = gqn;
        }

        if (tid == 0) {
            if (!isL2) __builtin_amdgcn_fence(__ATOMIC_RELEASE, "agent");
            __hip_atomic_store(&fOut[b].v, (unsigned)(ch + 1),
                               __ATOMIC_RELAXED, __HIP_MEMORY_SCOPE_AGENT);
        }
    }

    if (hh == 0) {
        cst[b * HH + tau] = c_;
        hst[b * HH + tau] = lastH;
    }
}

// ---------------------------------------------------------------------------
__global__ void fc_kernel(const float* __restrict__ h2,
                          const float* __restrict__ Wfc,
                          const float* __restrict__ bfc,
                          float* __restrict__ out)
{
    __shared__ float hs[256];
    int b = blockIdx.x, tid = threadIdx.x;
    hs[tid] = h2[b * HH + tid];
    __syncthreads();
    if (tid < NC) {
        float s = bfc[tid];
        for (int k = 0; k < 256; k++) s += hs[k] * Wfc[tid * 256 + k];
        out[b * NC + tid] = s;
    }
}

// ---------------------------------------------------------------------------
extern "C" void kernel_launch(void* const* d_in, const int* in_sizes, int n_in,
                              void* d_out, int out_size, void* d_ws, size_t ws_size,
                              hipStream_t stream)
{
    const float* x    = (const float*)d_in[0];
    const float* Wih0 = (const float*)d_in[1];
    const float* Whh0 = (const float*)d_in[2];
    const float* bih0 = (const float*)d_in[3];
    const float* bhh0 = (const float*)d_in[4];
    const float* Wih1 = (const float*)d_in[5];
    const float* Whh1 = (const float*)d_in[6];
    const float* bih1 = (const float*)d_in[7];
    const float* bhh1 = (const float*)d_in[8];
    const float* Wfc  = (const float*)d_in[9];
    const float* bfc  = (const float*)d_in[10];

    const size_t x16_b  = (size_t)BB * TT * HH * 2;      // 67.1 MB
    const size_t h1c_b  = x16_b;                          // 67.1 MB
    const size_t gxr_b  = (size_t)NR * CH * BB * H4 * 2;  // 16.8 MB
    const size_t w16_b  = (size_t)H4 * HH * 2;
    const size_t wpk_b  = (size_t)128 * 256 * 16;
    const size_t st_b   = (size_t)4 * BB * HH * 4;

    char* pp = (char*)d_ws;
    _Float16* x16  = (_Float16*)pp;  pp += x16_b;
    _Float16* h1c  = (_Float16*)pp;  pp += h1c_b;
    _Float16* gx1r = (_Float16*)pp;  pp += gxr_b;
    _Float16* gx2r = (_Float16*)pp;  pp += gxr_b;
    _Float16* w16a = (_Float16*)pp;  pp += w16_b;
    _Float16* w16b = (_Float16*)pp;  pp += w16_b;
    uint4*    wpk0 = (uint4*)pp;     pp += wpk_b;
    uint4*    wpk1 = (uint4*)pp;     pp += wpk_b;
    float*    hs1  = (float*)pp;
    float*    cs1  = hs1 + BB * HH;
    float*    hs2  = cs1 + BB * HH;
    float*    cs2  = hs2 + BB * HH;
    pp += st_b;
    Line* fG1 = (Line*)pp;
    Line* fL1 = fG1 + 64;
    Line* fG2 = fL1 + 64;
    Line* fL2 = fG2 + 64;

    // zero states + flags (contiguous)
    hipMemsetAsync(hs1, 0, st_b + 256 * sizeof(Line), stream);

    prep_w<<<128, 256, 0, stream>>>(Whh0, wpk0);
    prep_w<<<128, 256, 0, stream>>>(Whh1, wpk1);
    f32_to_f16<<<(BB * TT * HH / 8 + 255) / 256, 256, 0, stream>>>(x, x16, BB * TT * HH / 8);
    f32_to_f16<<<(H4 * HH / 8 + 255) / 256, 256, 0, stream>>>(Wih0, w16a, H4 * HH / 8);
    f32_to_f16<<<(H4 * HH / 8 + 255) / 256, 256, 0, stream>>>(Wih1, w16b, H4 * HH / 8);

    lstm_pipe<<<256, 512, 0, stream>>>(x16, w16a, w16b,
                                       bih0, bhh0, bih1, bhh1,
                                       wpk0, wpk1, gx1r, gx2r, h1c,
                                       hs1, cs1, hs2, cs2,
                                       fG1, fL1, fG2, fL2);

    fc_kernel<<<BB, 256, 0, stream>>>(hs2, Wfc, bfc, (float*)d_out);
}

// Round 23
// 3589.196 us; speedup vs baseline: 1.9428x; 1.0230x over previous
//
#include <hip/hip_runtime.h>
#include <hip/hip_bf16.h>

#define BB 64
#define TT 2048
#define HH 256
#define H4 1024
#define NC 10
#define CH 32            // steps per chunk
#define NCH (TT / CH)    // 64 chunks
#define NR 4             // gx ring slots

typedef _Float16 half2v __attribute__((ext_vector_type(2)));
typedef _Float16 half8  __attribute__((ext_vector_type(8)));
typedef float    f32x4  __attribute__((ext_vector_type(4)));

struct __align__(128) Line { unsigned v; unsigned pad[31]; };

__device__ __forceinline__ float fsig_(float x) {
    return __fdividef(1.f, 1.f + __expf(-x));
}
__device__ __forceinline__ float ftanh_(float x) {
    return 1.f - __fdividef(2.f, __expf(2.f * x) + 1.f);
}

__device__ __forceinline__ float fdot2_(unsigned wu, half2v hv, float acc) {
#if __has_builtin(__builtin_amdgcn_fdot2)
    return __builtin_amdgcn_fdot2(__builtin_bit_cast(half2v, wu), hv, acc, false);
#else
    half2v w = __builtin_bit_cast(half2v, wu);
    return acc + (float)w[0] * (float)hv[0] + (float)w[1] * (float)hv[1];
#endif
}

// pair sum via DPP quad_perm [1,0,3,2] (dpp_ctrl 0xB1): lane gets own + lane^1.
__device__ __forceinline__ float xpair_sum_(float a) {
    int ai = __builtin_bit_cast(int, a);
    int bi = __builtin_amdgcn_mov_dpp(ai, 0xB1, 0xF, 0xF, true);
    return a + __builtin_bit_cast(float, bi);
}

// wave-0 parallel poll of 64 flags; one acquire fence; releases whole WG.
__device__ __forceinline__ void wait_flags(Line* f, unsigned target, int tid) {
    if (tid < 64) {
        while (true) {
            unsigned v = __hip_atomic_load(&f[tid].v, __ATOMIC_RELAXED,
                                           __HIP_MEMORY_SCOPE_AGENT);
            if (__all(v >= target)) break;
            __builtin_amdgcn_s_sleep(2);
        }
        if (tid == 0)
            __builtin_amdgcn_fence(__ATOMIC_ACQUIRE, "agent");
    }
    __syncthreads();
}

// ---------------------------------------------------------------------------
__global__ void f32_to_f16(const float* __restrict__ in,
                           _Float16* __restrict__ out, int n8)
{
    int i = blockIdx.x * 256 + threadIdx.x;
    if (i >= n8) return;
    float4 v0 = ((const float4*)in)[2 * i];
    float4 v1 = ((const float4*)in)[2 * i + 1];
    half8 h;
    h[0] = (_Float16)v0.x; h[1] = (_Float16)v0.y;
    h[2] = (_Float16)v0.z; h[3] = (_Float16)v0.w;
    h[4] = (_Float16)v1.x; h[5] = (_Float16)v1.y;
    h[6] = (_Float16)v1.z; h[7] = (_Float16)v1.w;
    ((half8*)out)[i] = h;
}

// ---------------------------------------------------------------------------
__global__ void prep_w(const float* __restrict__ W, uint4* __restrict__ out)
{
    const int k2 = blockIdx.x, t = threadIdx.x;
    unsigned q4[4];
#pragma unroll
    for (int q = 0; q < 4; q++) {
        const float* wr = W + (size_t)(q * 256 + t) * 256 + 2 * k2;
        union { _Float16 h[2]; unsigned u; } cv;
        cv.h[0] = (_Float16)wr[0];
        cv.h[1] = (_Float16)wr[1];
        q4[q] = cv.u;
    }
    out[(size_t)k2 * 256 + t] = make_uint4(q4[0], q4[1], q4[2], q4[3]);
}

// ---------------------------------------------------------------------------
// 4-role pipelined persistent kernel, 256 WGs x 512 threads (R17 topology).
// REC engine v5b: INTRA-WAVE pairwise k-split + LANE-LINEAR wl layout.
// Wave w lane l: unit tau = w*32+(l>>1), half hh = l&1.
// wl[slice*512 + tau*2 + hh]; thread reads wl[s*512 + w*64 + lane]
// (w*64+lane == 2*tau+hh) -> consecutive lanes, conflict-free.
// Staging k2 map (R22 bug fixed): hh=0 -> 48+s, hh=1 -> 112+s (s in [0,16));
// resident tiers cover k2 hh*64+[0,48).
// Exchange = 4x DPP quad_perm + add; ONE barrier/step.
// ---------------------------------------------------------------------------
__global__ __launch_bounds__(512, 1)
void lstm_pipe(const _Float16* __restrict__ x16,
               const _Float16* __restrict__ w16a, const _Float16* __restrict__ w16b,
               const float* __restrict__ bih0, const float* __restrict__ bhh0,
               const float* __restrict__ bih1, const float* __restrict__ bhh1,
               const uint4* __restrict__ wpk0, const uint4* __restrict__ wpk1,
               _Float16* __restrict__ gx1r, _Float16* __restrict__ gx2r,
               _Float16* __restrict__ h1c,
               float* __restrict__ hs1, float* __restrict__ cs1,
               float* __restrict__ hs2, float* __restrict__ cs2,
               Line* __restrict__ fG1, Line* __restrict__ fL1,
               Line* __restrict__ fG2, Line* __restrict__ fL2)
{
    __shared__ __align__(16) unsigned char pool[1088 + 32 * 4096];
    _Float16* hlb = (_Float16*)pool;              // [2][272] halves
    uint4*    wl  = (uint4*)(pool + 1088);        // [16 slices][512] (128 KB)

    const int wg = blockIdx.x, tid = threadIdx.x;
    const int role = wg >> 6, sub = wg & 63;

    if (role == 1 || role == 2) {
        // ---------------- gemm worker (identical to R17) ----------------
        const bool isG2 = (role == 2);
        const _Float16* A  = isG2 ? h1c  : x16;
        const _Float16* Wm = isG2 ? w16b : w16a;
        const float* b1 = isG2 ? bih1 : bih0;
        const float* b2 = isG2 ? bhh1 : bhh0;
        _Float16* outr  = isG2 ? gx2r : gx1r;
        Line* fOut      = isG2 ? fG2  : fG1;

        const int v = tid >> 6, lane = tid & 63;
        const int lrow = lane & 15, lkg = lane >> 4;
        const int rquad = v & 3, nqh = v >> 2;
        const int tcl = sub & 31;
        const int n0 = (sub >> 5) * 512 + nqh * 256;

        const _Float16* wrow0 = Wm + (size_t)(n0 + lrow) * 256 + lkg * 8;

        for (int c = 0; c < NCH; c++) {
            if (isG2) {
                wait_flags(fL1, (unsigned)(c + 1), tid);
                if (c >= NR) wait_flags(fL2, (unsigned)(c - (NR - 1)), tid);
            } else {
                if (c >= NR) wait_flags(fL1, (unsigned)(c - (NR - 1)), tid);
            }
            const int tc = c * CH + tcl;
            const int slot = c % NR;
            const _Float16* arow =
                A + ((size_t)(rquad * 16 + lrow) * TT + tc) * 256 + lkg * 8;

            f32x4 acc[16];
#pragma unroll
            for (int j = 0; j < 16; j++) acc[j] = (f32x4)(0.f);
#pragma unroll
            for (int k0 = 0; k0 < 256; k0 += 32) {
                half8 a = *(const half8*)(arow + k0);
#pragma unroll
                for (int j = 0; j < 16; j++) {
                    half8 bf = *(const half8*)(wrow0 + (size_t)j * 16 * 256 + k0);
                    acc[j] = __builtin_amdgcn_mfma_f32_16x16x32_f16(a, bf, acc[j], 0, 0, 0);
                }
            }
            const int bout = rquad * 16 + lkg * 4;
#pragma unroll
            for (int j = 0; j < 16; j++) {
                int n = n0 + j * 16 + lrow;
                float bsum = b1[n] + b2[n];
                int u = n & 255, q = n >> 8;       // gate-interleaved target
#pragma unroll
                for (int r = 0; r < 4; r++) {
                    outr[((size_t)(slot * CH + tcl) * BB + bout + r) * H4 + u * 4 + q] =
                        (_Float16)(acc[j][r] + bsum);
                }
            }
            __syncthreads();
            if (tid == 0) {
                __builtin_amdgcn_fence(__ATOMIC_RELEASE, "agent");
                __hip_atomic_store(&fOut[sub].v, (unsigned)(c + 1),
                                   __ATOMIC_RELAXED, __HIP_MEMORY_SCOPE_AGENT);
            }
        }
        return;
    }

    // ---------------- recurrence (role 0 = L1, role 3 = L2) ----------------
    const bool isL2 = (role == 3);
    const uint4* wpk = isL2 ? wpk1 : wpk0;
    const _Float16* gxr = isL2 ? gx2r : gx1r;
    float* hst = isL2 ? hs2 : hs1;
    float* cst = isL2 ? cs2 : cs1;
    Line* fIn  = isL2 ? fG2 : fG1;
    Line* fOut = isL2 ? fL2 : fL1;
    const int b = sub;
    const int w = tid >> 6, lane = tid & 63;
    const int tau = w * 32 + (lane >> 1);     // unit
    const int hh  = lane & 1;                 // k-half (pairwise intra-wave)

    // stage LDS weight slices, lane-linear: wl[s*512 + tau*2 + hh]
    //   hh=0 -> k2 = 48+s ; hh=1 -> k2 = 112+s   (s in [0,16))
#pragma unroll
    for (int m = 0; m < 16; m++) {
        int e = m * 512 + tid;               // [0, 8192)
        int s = e >> 9;                      // slice
        int rem = e & 511;
        int tp = rem >> 1, hp = rem & 1;
        int k2g = hp ? (112 + s) : (48 + s);
        wl[e] = wpk[(size_t)k2g * 256 + tp];
    }

    // 48 resident quads: k2 = hh*64 + r (volatile: exactly-once, AGPR-backed)
    uint4 w4[48];
    {
        const volatile unsigned* wv = (const volatile unsigned*)wpk;
#pragma unroll
        for (int r = 0; r < 48; r++) {
            size_t base = ((size_t)(hh * 64 + r) * 256 + tau) * 4;
            w4[r].x = wv[base + 0];
            w4[r].y = wv[base + 1];
            w4[r].z = wv[base + 2];
            w4[r].w = wv[base + 3];
        }
    }

    // lane-linear read base: thread's quad for slice s is wl[s*512 + w*64 + lane]
    const uint4* wbase = wl + (w * 64 + lane);

    // state duplicated in both lanes of a pair (identical computation)
    float c_ = cst[b * HH + tau];
    float lastH = hst[b * HH + tau];
    if (hh == 0) hlb[tau] = (_Float16)lastH;
    __syncthreads();

    int p = 0;
    for (int ch = 0; ch < NCH; ch++) {
        wait_flags(fIn, (unsigned)(ch + 1), tid);
        const _Float16* gsl = gxr + (size_t)(ch % NR) * CH * BB * H4
                            + (size_t)b * H4 + tau * 4;
        uint2 gq = *(const uint2*)gsl;          // both pair-lanes load (same addr)

        for (int l = 0; l < CH; l++) {
            uint2 gqn = gq;
            if (l < CH - 1)
                gqn = *(const uint2*)(gsl + (size_t)(l + 1) * BB * H4);

            const uint4* hp4 = (const uint4*)(hlb + p * 272) + hh * 16;
            float a0 = 0.f, a1 = 0.f, a2 = 0.f, a3 = 0.f;

            // register tier: r = 4j+u, j in [0,12)
#pragma unroll
            for (int j = 0; j < 12; j++) {
                uint4 hq = hp4[j];
#pragma unroll
                for (int u = 0; u < 4; u++) {
                    half2v hv = __builtin_bit_cast(half2v, hq[u]);
                    uint4 ww = w4[4 * j + u];
                    a0 = fdot2_(ww.x, hv, a0);
                    a1 = fdot2_(ww.y, hv, a1);
                    a2 = fdot2_(ww.z, hv, a2);
                    a3 = fdot2_(ww.w, hv, a3);
                }
            }
            // LDS tier: j in [12,16), slice s = 4*(j-12)+u  (k2 = hh?112+s:48+s)
#pragma unroll
            for (int j = 12; j < 16; j++) {
                uint4 hq = hp4[j];
#pragma unroll
                for (int u = 0; u < 4; u++) {
                    uint4 ww = wbase[(4 * (j - 12) + u) * 512];
                    half2v hv = __builtin_bit_cast(half2v, hq[u]);
                    a0 = fdot2_(ww.x, hv, a0);
                    a1 = fdot2_(ww.y, hv, a1);
                    a2 = fdot2_(ww.z, hv, a2);
                    a3 = fdot2_(ww.w, hv, a3);
                }
            }

            // pairwise partial exchange: DPP quad_perm + add (pure VALU)
            a0 = xpair_sum_(a0);
            a1 = xpair_sum_(a1);
            a2 = xpair_sum_(a2);
            a3 = xpair_sum_(a3);

            // gates: both pair-lanes compute (redundant, parallel, identical)
            half2v glo = __builtin_bit_cast(half2v, gq.x);
            half2v ghi = __builtin_bit_cast(half2v, gq.y);
            float ig = fsig_(a0 + (float)glo[0]);
            float fg = fsig_(a1 + (float)glo[1]);
            float gg = ftanh_(a2 + (float)ghi[0]);
            float og = fsig_(a3 + (float)ghi[1]);
            c_ = fg * c_ + ig * gg;
            float h = og * ftanh_(c_);
            lastH = h;
            if (hh == 0) {
                if (!isL2)
                    h1c[((size_t)b * TT + ch * CH + l) * HH + tau] = (_Float16)h;
                hlb[(p ^ 1) * 272 + tau] = (_Float16)h;
            }
            __syncthreads();            // the ONE barrier per step
            p ^= 1;
            gq = gqn;
        }

        if (tid == 0) {
            if (!isL2) __builtin_amdgcn_fence(__ATOMIC_RELEASE, "agent");
            __hip_atomic_store(&fOut[b].v, (unsigned)(ch + 1),
                               __ATOMIC_RELAXED, __HIP_MEMORY_SCOPE_AGENT);
        }
    }

    if (hh == 0) {
        cst[b * HH + tau] = c_;
        hst[b * HH + tau] = lastH;
    }
}

// ---------------------------------------------------------------------------
__global__ void fc_kernel(const float* __restrict__ h2,
                          const float* __restrict__ Wfc,
                          const float* __restrict__ bfc,
                          float* __restrict__ out)
{
    __shared__ float hs[256];
    int b = blockIdx.x, tid = threadIdx.x;
    hs[tid] = h2[b * HH + tid];
    __syncthreads();
    if (tid < NC) {
        float s = bfc[tid];
        for (int k = 0; k < 256; k++) s += hs[k] * Wfc[tid * 256 + k];
        out[b * NC + tid] = s;
    }
}

// ---------------------------------------------------------------------------
extern "C" void kernel_launch(void* const* d_in, const int* in_sizes, int n_in,
                              void* d_out, int out_size, void* d_ws, size_t ws_size,
                              hipStream_t stream)
{
    const float* x    = (const float*)d_in[0];
    const float* Wih0 = (const float*)d_in[1];
    const float* Whh0 = (const float*)d_in[2];
    const float* bih0 = (const float*)d_in[3];
    const float* bhh0 = (const float*)d_in[4];
    const float* Wih1 = (const float*)d_in[5];
    const float* Whh1 = (const float*)d_in[6];
    const float* bih1 = (const float*)d_in[7];
    const float* bhh1 = (const float*)d_in[8];
    const float* Wfc  = (const float*)d_in[9];
    const float* bfc  = (const float*)d_in[10];

    const size_t x16_b  = (size_t)BB * TT * HH * 2;      // 67.1 MB
    const size_t h1c_b  = x16_b;                          // 67.1 MB
    const size_t gxr_b  = (size_t)NR * CH * BB * H4 * 2;  // 16.8 MB
    const size_t w16_b  = (size_t)H4 * HH * 2;
    const size_t wpk_b  = (size_t)128 * 256 * 16;
    const size_t st_b   = (size_t)4 * BB * HH * 4;

    char* pp = (char*)d_ws;
    _Float16* x16  = (_Float16*)pp;  pp += x16_b;
    _Float16* h1c  = (_Float16*)pp;  pp += h1c_b;
    _Float16* gx1r = (_Float16*)pp;  pp += gxr_b;
    _Float16* gx2r = (_Float16*)pp;  pp += gxr_b;
    _Float16* w16a = (_Float16*)pp;  pp += w16_b;
    _Float16* w16b = (_Float16*)pp;  pp += w16_b;
    uint4*    wpk0 = (uint4*)pp;     pp += wpk_b;
    uint4*    wpk1 = (uint4*)pp;     pp += wpk_b;
    float*    hs1  = (float*)pp;
    float*    cs1  = hs1 + BB * HH;
    float*    hs2  = cs1 + BB * HH;
    float*    cs2  = hs2 + BB * HH;
    pp += st_b;
    Line* fG1 = (Line*)pp;
    Line* fL1 = fG1 + 64;
    Line* fG2 = fL1 + 64;
    Line* fL2 = fG2 + 64;

    // zero states + flags (contiguous)
    hipMemsetAsync(hs1, 0, st_b + 256 * sizeof(Line), stream);

    prep_w<<<128, 256, 0, stream>>>(Whh0, wpk0);
    prep_w<<<128, 256, 0, stream>>>(Whh1, wpk1);
    f32_to_f16<<<(BB * TT * HH / 8 + 255) / 256, 256, 0, stream>>>(x, x16, BB * TT * HH / 8);
    f32_to_f16<<<(H4 * HH / 8 + 255) / 256, 256, 0, stream>>>(Wih0, w16a, H4 * HH / 8);
    f32_to_f16<<<(H4 * HH / 8 + 255) / 256, 256, 0, stream>>>(Wih1, w16b, H4 * HH / 8);

    lstm_pipe<<<256, 512, 0, stream>>>(x16, w16a, w16b,
                                       bih0, bhh0, bih1, bhh1,
                                       wpk0, wpk1, gx1r, gx2r, h1c,
                                       hs1, cs1, hs2, cs2,
                                       fG1, fL1, fG2, fL2);

    fc_kernel<<<BB, 256, 0, stream>>>(hs2, Wfc, bfc, (float*)d_out);
}